// Round 2
// baseline (461.650 us; speedup 1.0000x reference)
//
#include <hip/hip_runtime.h>
#include <hip/hip_fp16.h>

// Problem constants (reference: D=4096, K=128, B=4, S=4096)
#define DD 4096
#define KK 128
#define MAXHC 48      // cap on ceil(max_bucket_size/2); mean bucket=32, std 5.6 -> 96 is >11 sigma
#define XL2 4112      // u32 stride of one packed-pair row (4096 data + sentinel + pad; 16448 B, 16B-aligned)
#define QVC_OFF 24832 // byte offset of qvC pack in ws (16B aligned, past perm2+maxh)

union H2 { unsigned int u; __half2 h; };

static __device__ __forceinline__ unsigned int pkh2(float lo, float hi) {
    H2 r; r.h = __floats2half2_rn(lo, hi); return r.u;
}

// ---------------------------------------------------------------------------
// Setup kernel (2 blocks).
// Block 0: thread-major padded permutation (unchanged layout):
//   perm2 (ushort): iteration i, thread tid -> offset (i>>1)*512 + tid*2 + (i&1)
//   Bucket c split round-robin between threads 2c (half 0) and 2c+1.
//   Pads hold index DD (=4096) -> zeroed LDS sentinel in the main kernel.
// Block 1: qvC[c4*128 + k] = {qv[(4c4+i)*128 + k], i=0..3} (float4, 64 KB).
// ---------------------------------------------------------------------------
__global__ void vq_build(const float* __restrict__ qv,
                         const int* __restrict__ assign,
                         unsigned short* __restrict__ perm2,
                         int* __restrict__ maxh,
                         float4* __restrict__ qvC) {
    const int tid = threadIdx.x;

    if (blockIdx.x == 1) {
        for (int idx = tid; idx < 4096; idx += 256) {
            const int c4 = idx >> 7;
            const int k  = idx & (KK - 1);
            float4 v;
            v.x = qv[(4 * c4 + 0) * KK + k];
            v.y = qv[(4 * c4 + 1) * KK + k];
            v.z = qv[(4 * c4 + 2) * KK + k];
            v.w = qv[(4 * c4 + 3) * KK + k];
            qvC[idx] = v;
        }
        return;
    }

    __shared__ int cnt[KK];
    __shared__ int off[KK];

    if (tid < KK) cnt[tid] = 0;
    for (int i = tid; i < MAXHC * 256; i += 256)
        perm2[i] = (unsigned short)DD;
    __syncthreads();

    for (int j = tid; j < DD; j += 256)
        atomicAdd(&cnt[assign[j]], 1);
    __syncthreads();

    if (tid == 0) {
        int m = 0;
        for (int c = 0; c < KK; ++c) {
            off[c] = 0;
            int h = (cnt[c] + 1) >> 1;
            if (h > m) m = h;
        }
        *maxh = (m < MAXHC) ? m : MAXHC;
    }
    __syncthreads();

    for (int j = tid; j < DD; j += 256) {
        const int c = assign[j];
        const int p = atomicAdd(&off[c], 1);
        const int i = p >> 1;
        const int th = 2 * c + (p & 1);
        if (i < MAXHC)
            perm2[(i >> 1) * 512 + th * 2 + (i & 1)] = (unsigned short)j;
    }
}

// ---------------------------------------------------------------------------
// Main kernel: one block per FOUR token rows.
//   x staged in LDS as packed half2 pairs: xp[j] = (x[t0][j], x[t1][j]),
//   xp[XL2+j] = (x[t2][j], x[t3][j]) -> 33 KB total, 4 blocks/CU retained.
//   Phase 1: one ds_read_b32 per (index, token-pair); fp32 accumulation.
//   Phase 2: thread 2k+h covers c-half h for all 4 tokens (16 float4 qvC
//            loads reused 4x); lane-pair shfl combine; qm4[k] = {tok0..3}.
//   Phase 3: one b128 qm4 gather per assign index serves all 4 output rows.
// ---------------------------------------------------------------------------
__global__ __launch_bounds__(256) void vq_main(
    const float* __restrict__ x,        // [T, D]
    const int*   __restrict__ assign,   // [D]
    const float* __restrict__ bias,     // [D]
    const unsigned int* __restrict__ pu,// perm2 as packed uint pairs
    const int* __restrict__ maxh,
    const float4* __restrict__ qvC,     // packed [32][128] float4
    float* __restrict__ out)            // [T, D]
{
    __shared__ unsigned int xp[2 * XL2];   // packed half2: [0]=tok(0,1), [XL2]=tok(2,3)
    __shared__ float xs[4 * KK];           // bucket sums, planar per token
    __shared__ float4 qm4[KK];             // qm4[k] = {qm[t0][k]..qm[t3][k]}

    const int t0  = blockIdx.x * 4;
    const int tid = threadIdx.x;

    // Phase 0: stage 4 rows, convert+pack to half2 pairs. Coalesced float4 in,
    // conflict-free uint4 LDS writes out.
    {
        const float4* r0 = reinterpret_cast<const float4*>(x + (size_t)(t0 + 0) * DD);
        const float4* r1 = reinterpret_cast<const float4*>(x + (size_t)(t0 + 1) * DD);
        const float4* r2 = reinterpret_cast<const float4*>(x + (size_t)(t0 + 2) * DD);
        const float4* r3 = reinterpret_cast<const float4*>(x + (size_t)(t0 + 3) * DD);
        uint4* pa = reinterpret_cast<uint4*>(xp);
        uint4* pb = reinterpret_cast<uint4*>(xp + XL2);
        #pragma unroll
        for (int i = 0; i < 4; ++i) {
            const int idx = tid + i * 256;
            const float4 a = r0[idx];
            const float4 b = r1[idx];
            const float4 c = r2[idx];
            const float4 d = r3[idx];
            uint4 wa, wb;
            wa.x = pkh2(a.x, b.x); wa.y = pkh2(a.y, b.y);
            wa.z = pkh2(a.z, b.z); wa.w = pkh2(a.w, b.w);
            wb.x = pkh2(c.x, d.x); wb.y = pkh2(c.y, d.y);
            wb.z = pkh2(c.z, d.z); wb.w = pkh2(c.w, d.w);
            pa[idx] = wa;
            pb[idx] = wb;
        }
        if (tid == 0) { xp[DD] = 0u; xp[XL2 + DD] = 0u; }  // pad sentinel -> 0
    }
    __syncthreads();

    // Phase 1: bucket sums, no atomics. Thread tid = 2c+h owns half h of bucket c,
    // for all 4 tokens. One b32 read serves a token pair.
    {
        const int mh2 = (*maxh + 1) >> 1;          // packed-pair iterations (~13)
        float s0 = 0.f, s1 = 0.f, s2 = 0.f, s3 = 0.f;
        for (int ii = 0; ii < mh2; ++ii) {
            const unsigned int pp = pu[ii * 256 + tid];  // coalesced, L1/L2-hit
            const int i0 = pp & 0xFFFFu;
            const int i1 = pp >> 16;
            H2 wa0, wb0, wa1, wb1;
            wa0.u = xp[i0];        wb0.u = xp[XL2 + i0];
            wa1.u = xp[i1];        wb1.u = xp[XL2 + i1];
            s0 += __low2float(wa0.h);  s1 += __high2float(wa0.h);
            s2 += __low2float(wb0.h);  s3 += __high2float(wb0.h);
            s0 += __low2float(wa1.h);  s1 += __high2float(wa1.h);
            s2 += __low2float(wb1.h);  s3 += __high2float(wb1.h);
        }
        s0 += __shfl_xor(s0, 1);   // combine the two bucket halves
        s1 += __shfl_xor(s1, 1);
        s2 += __shfl_xor(s2, 1);
        s3 += __shfl_xor(s3, 1);
        if ((tid & 1) == 0) {
            const int c = tid >> 1;
            xs[c]          = s0;
            xs[KK + c]     = s1;
            xs[2 * KK + c] = s2;
            xs[3 * KK + c] = s3;
        }
    }
    __syncthreads();

    // Phase 2: thread 2k+h computes the c-half h of qm[*][k] for all 4 tokens.
    // qvC loads: 16 float4, each reused across 4 tokens (16 KB/token from L2).
    {
        const int k = tid >> 1;
        const int h = tid & 1;
        const float4* xsf4 = reinterpret_cast<const float4*>(xs);  // [tt*32 + c4]
        float4 acc[4];
        acc[0] = acc[1] = acc[2] = acc[3] = make_float4(0.f, 0.f, 0.f, 0.f);
        #pragma unroll 4
        for (int c4 = 0; c4 < 16; ++c4) {
            const int cg = h * 16 + c4;
            const float4 q = qvC[cg * KK + k];
            #pragma unroll
            for (int tt = 0; tt < 4; ++tt) {
                const float4 v = xsf4[tt * 32 + cg];   // 2-address LDS broadcast
                acc[tt].x += q.x * v.x;
                acc[tt].y += q.y * v.y;
                acc[tt].z += q.z * v.z;
                acc[tt].w += q.w * v.w;
            }
        }
        float r0 = (acc[0].x + acc[0].y) + (acc[0].z + acc[0].w);
        float r1 = (acc[1].x + acc[1].y) + (acc[1].z + acc[1].w);
        float r2 = (acc[2].x + acc[2].y) + (acc[2].z + acc[2].w);
        float r3 = (acc[3].x + acc[3].y) + (acc[3].z + acc[3].w);
        r0 += __shfl_xor(r0, 1);   // combine the two c-halves (lanes 2k, 2k+1)
        r1 += __shfl_xor(r1, 1);
        r2 += __shfl_xor(r2, 1);
        r3 += __shfl_xor(r3, 1);
        if (h == 0) qm4[k] = make_float4(r0, r1, r2, r3);
    }
    __syncthreads();

    // Phase 3: out[t,d] = qm4[a[d]][t] + bias[d]; one b128 gather per index
    // serves 4 rows; float4 coalesced stores.
    {
        const int4*   a4 = reinterpret_cast<const int4*>(assign);
        const float4* b4 = reinterpret_cast<const float4*>(bias);
        float4* o0 = reinterpret_cast<float4*>(out + (size_t)(t0 + 0) * DD);
        float4* o1 = reinterpret_cast<float4*>(out + (size_t)(t0 + 1) * DD);
        float4* o2 = reinterpret_cast<float4*>(out + (size_t)(t0 + 2) * DD);
        float4* o3 = reinterpret_cast<float4*>(out + (size_t)(t0 + 3) * DD);
        #pragma unroll
        for (int i = 0; i < 4; ++i) {
            const int idx = tid + i * 256;
            const int4   a = a4[idx];
            const float4 b = b4[idx];
            const float4 qx = qm4[a.x];
            const float4 qy = qm4[a.y];
            const float4 qz = qm4[a.z];
            const float4 qw = qm4[a.w];
            float4 s;
            s.x = qx.x + b.x; s.y = qy.x + b.y; s.z = qz.x + b.z; s.w = qw.x + b.w;
            o0[idx] = s;
            s.x = qx.y + b.x; s.y = qy.y + b.y; s.z = qz.y + b.z; s.w = qw.y + b.w;
            o1[idx] = s;
            s.x = qx.z + b.x; s.y = qy.z + b.y; s.z = qz.z + b.z; s.w = qw.z + b.w;
            o2[idx] = s;
            s.x = qx.w + b.x; s.y = qy.w + b.y; s.z = qz.w + b.z; s.w = qw.w + b.w;
            o3[idx] = s;
        }
    }
}

extern "C" void kernel_launch(void* const* d_in, const int* in_sizes, int n_in,
                              void* d_out, int out_size, void* d_ws, size_t ws_size,
                              hipStream_t stream) {
    const float* x      = (const float*)d_in[0];  // [B,S,D] fp32
    const float* qv     = (const float*)d_in[1];  // [D,K]   fp32
    const int*   assign = (const int*)d_in[2];    // [D]     int32
    const float* bias   = (const float*)d_in[3];  // [D]     fp32
    float*       out    = (float*)d_out;

    // ws layout: [perm2: 24576 B][maxh: 4 B][pad][qvC: 65536 B @ QVC_OFF]
    unsigned short* perm2 = (unsigned short*)d_ws;
    int*    maxh = (int*)((char*)d_ws + MAXHC * 256 * sizeof(unsigned short));
    float4* qvC  = (float4*)((char*)d_ws + QVC_OFF);

    const int T = in_sizes[0] / DD;               // 16384 tokens

    vq_build<<<dim3(2), dim3(256), 0, stream>>>(qv, assign, perm2, maxh, qvC);
    vq_main<<<dim3(T / 4), dim3(256), 0, stream>>>(
        x, assign, bias, (const unsigned int*)perm2, maxh, qvC, out);
}